// Round 4
// baseline (271.143 us; speedup 1.0000x reference)
//
#include <hip/hip_runtime.h>

using u16 = unsigned short;
typedef float  f32x4 __attribute__((ext_vector_type(4)));
typedef __bf16 bf8_t __attribute__((ext_vector_type(8)));
typedef u16    u16x4 __attribute__((ext_vector_type(4)));
typedef unsigned int u32x2 __attribute__((ext_vector_type(2)));

#define NB 2
#define NH 16
#define NT 2048
#define ND 32
#define NC 512
#define QK_SCALE 0.17677669529663687f   // 1/sqrt(32)
#define LOG2E    1.4426950408889634f

__device__ __forceinline__ u16 f2bf(float f) {
  unsigned int u = __float_as_uint(f);
  u += 0x7fffu + ((u >> 16) & 1u);      // RNE
  return (u16)(u >> 16);
}

__device__ __forceinline__ unsigned int cvt_pk_bf16(float a, float b) {
  unsigned int r;
  asm("v_cvt_pk_bf16_f32 %0, %1, %2" : "=v"(r) : "v"(a), "v"(b));
  return r;                             // lo16 = bf16(a), hi16 = bf16(b)
}

__device__ __forceinline__ f32x4 mfma16(bf8_t a, bf8_t b, f32x4 c) {
  return __builtin_amdgcn_mfma_f32_16x16x32_bf16(a, b, c, 0, 0, 0);
}

// ---------------------------------------------------------------------------
// Kernel 1: weights -> bf16 (Wq pre-scaled by log2e/sqrt(D)); mask -> float
// (maskf = 0/1, maskb = 0/-1e30 additive bias) and mask chunk of d_out.
// ---------------------------------------------------------------------------
__global__ __launch_bounds__(256) void convert_kernel(
    const float* __restrict__ Wq, const float* __restrict__ Wk,
    const float* __restrict__ Wv, const float* __restrict__ Wp,
    const void* __restrict__ mraw,
    u16* __restrict__ Wc, float* __restrict__ maskf, float* __restrict__ maskb,
    float* __restrict__ outtail) {
  int bid = blockIdx.x;
  if (bid < 1024) {
    int idx = (bid * 256 + (int)threadIdx.x) * 4;
    int m   = idx >> 18;          // 262144 elements per matrix
    int off = idx & 262143;
    const float* W = (m == 0) ? Wq : (m == 1) ? Wk : (m == 2) ? Wv : Wp;
    float s = (m == 0) ? (QK_SCALE * LOG2E) : 1.0f;
    f32x4 wv = *(const f32x4*)(W + off);
    u16x4 pk;
    #pragma unroll
    for (int r = 0; r < 4; ++r) pk[r] = f2bf(wv[r] * s);
    *(u16x4*)(Wc + (size_t)m * (NC * NC) + off) = pk;
  } else {
    unsigned int w0 = *(const unsigned int*)mraw;   // bool-bytes vs int32
    bool intlay = (w0 == 1u);
    #pragma unroll
    for (int kk = 0; kk < 16; ++kk) {
      int j = (int)threadIdx.x + kk * 256;   // 0..4095 = NB*NT
      float mv;
      if (intlay) mv = ((const int*)mraw)[j] ? 1.0f : 0.0f;
      else        mv = ((const unsigned char*)mraw)[j] ? 1.0f : 0.0f;
      maskf[j]   = mv;
      maskb[j]   = (mv - 1.0f) * 1e30f;
      outtail[j] = mv;
    }
  }
}

// ---------------------------------------------------------------------------
// Kernel 2: q/k/v (B,C,T) f32 -> Xt (B,T,C) bf16 (LDS tile transpose).
// ---------------------------------------------------------------------------
__global__ __launch_bounds__(256) void transpose_kernel(
    const float* __restrict__ q, const float* __restrict__ k,
    const float* __restrict__ v, u16* __restrict__ Xt) {
  __shared__ float tile[32][33];
  int z = blockIdx.z;
  int m = z >> 1, b = z & 1;
  const float* src = (m == 0) ? q : (m == 1) ? k : v;
  int t0 = blockIdx.x * 32, c0 = blockIdx.y * 32;
  int tx = threadIdx.x, ty = threadIdx.y;
  #pragma unroll
  for (int j = 0; j < 4; ++j)
    tile[ty + j * 8][tx] = src[(size_t)(b * NC + c0 + ty + j * 8) * NT + t0 + tx];
  __syncthreads();
  u16* dst = Xt + (size_t)m * (NB * NT * NC);
  #pragma unroll
  for (int j = 0; j < 4; ++j)
    dst[((size_t)b * NT + t0 + ty + j * 8) * NC + c0 + tx] = f2bf(tile[tx][ty + j * 8]);
}

// ---------------------------------------------------------------------------
// Kernel 3: 3 input projections (R2-proven M=64 x N=128 tile, direct frags).
// grid (8, 32, 3).  z: 0=Q -> (B,H,T,D) scaled; 1=K -> (B,H,T,D);
// 2=V -> (B,C,T) masked.
// ---------------------------------------------------------------------------
__global__ __launch_bounds__(256) void proj_kernel(
    const u16* __restrict__ Wc, const u16* __restrict__ Xt,
    const float* __restrict__ bq, const float* __restrict__ bk, const float* __restrict__ bv,
    u16* __restrict__ Qw, u16* __restrict__ Kw, u16* __restrict__ Vw,
    const float* __restrict__ maskf) {
  int z = blockIdx.z;
  const u16* W = Wc + (size_t)z * (NC * NC);
  const float* bias = (z == 0) ? bq : (z == 1) ? bk : bv;
  int tid = threadIdx.x, wid = tid >> 6, lane = tid & 63;
  int lq = lane & 15, g = lane >> 4;
  int om0 = blockIdx.x * 64;
  int b   = blockIdx.y >> 4;
  int t0  = (blockIdx.y & 15) * 128 + wid * 32;
  const u16* Xb = Xt + (size_t)z * (NB * NT * NC) + (size_t)b * NT * NC;

  const f32x4 zero = {0.f, 0.f, 0.f, 0.f};
  f32x4 acc[4][2];
  #pragma unroll
  for (int mt = 0; mt < 4; ++mt)
    #pragma unroll
    for (int nt = 0; nt < 2; ++nt) acc[mt][nt] = zero;

  for (int ks = 0; ks < 16; ++ks) {       // K = 512, BK = 32
    bf8_t af[4], bfr[2];
    #pragma unroll
    for (int mt = 0; mt < 4; ++mt)
      af[mt] = *(const bf8_t*)(W + (size_t)(om0 + mt * 16 + lq) * NC + ks * 32 + 8 * g);
    #pragma unroll
    for (int nt = 0; nt < 2; ++nt)
      bfr[nt] = *(const bf8_t*)(Xb + (size_t)(t0 + nt * 16 + lq) * NC + ks * 32 + 8 * g);
    #pragma unroll
    for (int mt = 0; mt < 4; ++mt)
      #pragma unroll
      for (int nt = 0; nt < 2; ++nt)
        acc[mt][nt] = mfma16(af[mt], bfr[nt], acc[mt][nt]);
  }

  float sc = (z == 0) ? (QK_SCALE * LOG2E) : 1.0f;
  #pragma unroll
  for (int mt = 0; mt < 4; ++mt) {
    int ob = om0 + mt * 16 + 4 * g;       // 4 consecutive output channels (regs)
    float b4[4];
    #pragma unroll
    for (int r = 0; r < 4; ++r) b4[r] = bias[ob + r] * sc;
    #pragma unroll
    for (int nt = 0; nt < 2; ++nt) {
      int t = t0 + nt * 16 + lq;
      if (z < 2) {
        u16x4 pk;
        #pragma unroll
        for (int r = 0; r < 4; ++r) pk[r] = f2bf(acc[mt][nt][r] + b4[r]);
        u16* dst = (z == 0) ? Qw : Kw;
        *(u16x4*)(dst + ((size_t)(b * NH + (ob >> 5)) * NT + t) * ND + (ob & 31)) = pk;
      } else {
        float mv = maskf[b * NT + t];     // vm = vh * mask
        #pragma unroll
        for (int r = 0; r < 4; ++r)
          Vw[(size_t)(b * NC + ob + r) * NT + t] = f2bf((acc[mt][nt][r] + b4[r]) * mv);
      }
    }
  }
}

// ---------------------------------------------------------------------------
// Kernel 4: flash attention, split-KV (flash-decoding). R2 per-wave structure
// (32 q-rows/wave, full K-frag reuse) but each block handles half the key
// range (z=0: kt 0-7, z=1: kt 8-15) -> 1024 blocks = 4 blocks/CU.
// Writes unnormalized f32 partial O + (m,l) per query; combine in outproj.
// ---------------------------------------------------------------------------
__global__ __launch_bounds__(256, 4) void attn_kernel(
    const u16* __restrict__ Qw, const u16* __restrict__ Kw, const u16* __restrict__ Vw,
    float* __restrict__ Op, float* __restrict__ ml, const float* __restrict__ maskb) {
  __shared__ u16 plds[4][32][128];        // per-wave [tq][tk] bf16, swizzled
  int tid = threadIdx.x, wid = tid >> 6, lane = tid & 63;
  int lq = lane & 15, g = lane >> 4;
  int bh = blockIdx.y, b = bh >> 4, h = bh & 15;
  int z  = blockIdx.z;                    // KV half
  int q0 = blockIdx.x * 128 + wid * 32;
  const u16* Qb = Qw + (size_t)bh * NT * ND;
  const u16* Kb = Kw + (size_t)bh * NT * ND;
  const u16* Vb = Vw + (size_t)(b * NC + h * ND) * NT;
  const float* mbp = maskb + b * NT;
  char* pbase = (char*)&plds[wid][0][0];

  bf8_t ones;
  #pragma unroll
  for (int j = 0; j < 8; ++j) ones[j] = (__bf16)1.0f;

  bf8_t qf[2];                            // Q rows held for whole k-loop
  #pragma unroll
  for (int c = 0; c < 2; ++c)
    qf[c] = *(const bf8_t*)(Qb + (size_t)(q0 + c * 16 + lq) * ND + 8 * g);

  const f32x4 zero = {0.f, 0.f, 0.f, 0.f};
  f32x4 acc[3][2];                        // [0..1]=O^T frags, [2]=row-sum
  #pragma unroll
  for (int dt = 0; dt < 3; ++dt)
    #pragma unroll
    for (int c = 0; c < 2; ++c) acc[dt][c] = zero;
  float mrun[2] = {0.f, 0.f};             // running max (log2 units)

  for (int kt = z * 8; kt < z * 8 + 8; ++kt) {   // half the Tk tiles
    int tkb = kt * 128;
    // S^T = K @ Q^T + mask_bias (bias rides C-in; C/D row = tk)
    f32x4 st[8][2];
    #pragma unroll
    for (int rt = 0; rt < 8; ++rt) {
      f32x4 bias = *(const f32x4*)(mbp + tkb + rt * 16 + 4 * g);
      bf8_t kf = *(const bf8_t*)(Kb + (size_t)(tkb + rt * 16 + lq) * ND + 8 * g);
      st[rt][0] = mfma16(kf, qf[0], bias);
      st[rt][1] = mfma16(kf, qf[1], bias);
    }
    // V fragments: issue now, consumed after softmax (latency hides under exp)
    bf8_t vf[2][4];
    #pragma unroll
    for (int dt = 0; dt < 2; ++dt)
      #pragma unroll
      for (int kk = 0; kk < 4; ++kk)
        vf[dt][kk] = *(const bf8_t*)(Vb + (size_t)(dt * 16 + lq) * NT + tkb + kk * 32 + 8 * g);

    // online softmax per tq (lane-local in lane&15)
    #pragma unroll
    for (int c = 0; c < 2; ++c) {
      float tm = -1e30f;
      #pragma unroll
      for (int rt = 0; rt < 8; ++rt) {
        tm = fmaxf(fmaxf(st[rt][c][0], st[rt][c][1]), tm);
        tm = fmaxf(fmaxf(st[rt][c][2], st[rt][c][3]), tm);
      }
      tm = fmaxf(tm, __shfl_xor(tm, 16));
      tm = fmaxf(tm, __shfl_xor(tm, 32));
      if (__any(tm > mrun[c] + 2.0f)) {   // defer-max: rescale rarely
        float mnew = fmaxf(mrun[c], tm);
        float al = __builtin_amdgcn_exp2f(mrun[c] - mnew);
        mrun[c] = mnew;
        acc[0][c] *= al; acc[1][c] *= al; acc[2][c] *= al;
      }
      float nm = -mrun[c];
      int row = c * 16 + lq;
      #pragma unroll
      for (int rt = 0; rt < 8; ++rt) {    // exp2 + pack + LDS write
        float p0 = __builtin_amdgcn_exp2f(st[rt][c][0] + nm);
        float p1 = __builtin_amdgcn_exp2f(st[rt][c][1] + nm);
        float p2 = __builtin_amdgcn_exp2f(st[rt][c][2] + nm);
        float p3 = __builtin_amdgcn_exp2f(st[rt][c][3] + nm);
        u32x2 w;
        w[0] = cvt_pk_bf16(p0, p1);
        w[1] = cvt_pk_bf16(p2, p3);
        *(u32x2*)(pbase + row * 256 + ((rt * 32 + 8 * g) ^ ((row & 7) << 4))) = w;
      }
    }
    // O^T += V @ P^T ; row-sum += ones @ P^T (matrix pipe)
    #pragma unroll
    for (int kk = 0; kk < 4; ++kk) {
      bf8_t pf[2];
      #pragma unroll
      for (int c = 0; c < 2; ++c) {
        int row = c * 16 + lq;
        pf[c] = *(const bf8_t*)(pbase + row * 256 + ((kk * 64 + 16 * g) ^ ((row & 7) << 4)));
      }
      #pragma unroll
      for (int c = 0; c < 2; ++c) {
        acc[0][c] = mfma16(vf[0][kk], pf[c], acc[0][c]);
        acc[1][c] = mfma16(vf[1][kk], pf[c], acc[1][c]);
        acc[2][c] = mfma16(ones,      pf[c], acc[2][c]);
      }
    }
  }
  // store UNNORMALIZED partial O (f32) + (m, l) per query
  size_t pofs = (size_t)z * NB * NH * NT * ND;
  size_t mofs = (size_t)z * NB * NH * NT;
  #pragma unroll
  for (int c = 0; c < 2; ++c) {
    int t = q0 + c * 16 + lq;
    if (g == 0) {
      float2 mlv; mlv.x = mrun[c]; mlv.y = acc[2][c][0];
      *(float2*)(ml + (mofs + (size_t)bh * NT + t) * 2) = mlv;
    }
    #pragma unroll
    for (int dt = 0; dt < 2; ++dt)
      *(f32x4*)(Op + pofs + ((size_t)bh * NT + t) * ND + dt * 16 + 4 * g) = acc[dt][c];
  }
}

// ---------------------------------------------------------------------------
// Kernel 5: output projection with inline split-KV combine.
// B-fragment per head ks: o = O1*c1 + O2*c2 (unnormalized f32 partials,
// c_i = 2^(m_i - m) / (l1*2^(m1-m) + l2*2^(m2-m))), packed to bf16.
// M32 x (4 waves x 16 t) blocks, grid (16, 64) = 1024 blocks.
// ---------------------------------------------------------------------------
__global__ __launch_bounds__(256, 4) void outproj_kernel(
    const u16* __restrict__ Wc, const float* __restrict__ Op,
    const float* __restrict__ ml,
    const float* __restrict__ bp, float* __restrict__ out,
    const float* __restrict__ maskf) {
  const u16* W = Wc + (size_t)3 * NC * NC;
  int tid = threadIdx.x, wid = tid >> 6, lane = tid & 63;
  int lq = lane & 15, g = lane >> 4;
  int om0 = blockIdx.x * 32;
  int b   = blockIdx.y >> 5;
  int t0  = (blockIdx.y & 31) * 64 + wid * 16;
  int t   = t0 + lq;

  const u16* Wr0 = W + (size_t)(om0 + lq) * NC + 8 * g;
  const u16* Wr1 = W + (size_t)(om0 + 16 + lq) * NC + 8 * g;
  const size_t PS = (size_t)NB * NH * NT * ND;   // partial stride (f32 elems)
  const size_t MS = (size_t)NB * NH * NT;        // ml stride (pairs)

  const f32x4 zero = {0.f, 0.f, 0.f, 0.f};
  f32x4 acc0 = zero, acc1 = zero;

  for (int ks = 0; ks < 16; ++ks) {       // ks == head index; d-block = 8g
    bf8_t a0 = *(const bf8_t*)(Wr0 + ks * 32);
    bf8_t a1 = *(const bf8_t*)(Wr1 + ks * 32);
    size_t qb = (size_t)(b * NH + ks) * NT + t;
    float2 v1 = *(const float2*)(ml + qb * 2);
    float2 v2 = *(const float2*)(ml + (MS + qb) * 2);
    size_t ob = qb * ND + 8 * g;
    f32x4 o1a = *(const f32x4*)(Op + ob);
    f32x4 o1b = *(const f32x4*)(Op + ob + 4);
    f32x4 o2a = *(const f32x4*)(Op + PS + ob);
    f32x4 o2b = *(const f32x4*)(Op + PS + ob + 4);
    float m  = fmaxf(v1.x, v2.x);
    float e1 = __builtin_amdgcn_exp2f(v1.x - m);
    float e2 = __builtin_amdgcn_exp2f(v2.x - m);
    float inv = 1.0f / (v1.y * e1 + v2.y * e2);
    float c1 = e1 * inv, c2 = e2 * inv;
    union { bf8_t v; unsigned int u[4]; } xf;
    xf.u[0] = cvt_pk_bf16(o1a[0] * c1 + o2a[0] * c2, o1a[1] * c1 + o2a[1] * c2);
    xf.u[1] = cvt_pk_bf16(o1a[2] * c1 + o2a[2] * c2, o1a[3] * c1 + o2a[3] * c2);
    xf.u[2] = cvt_pk_bf16(o1b[0] * c1 + o2b[0] * c2, o1b[1] * c1 + o2b[1] * c2);
    xf.u[3] = cvt_pk_bf16(o1b[2] * c1 + o2b[2] * c2, o1b[3] * c1 + o2b[3] * c2);
    acc0 = mfma16(a0, xf.v, acc0);
    acc1 = mfma16(a1, xf.v, acc1);
  }
  float mv = maskf[b * NT + t];
  #pragma unroll
  for (int mt = 0; mt < 2; ++mt) {
    int ob = om0 + mt * 16 + 4 * g;
    const f32x4& a = mt ? acc1 : acc0;
    #pragma unroll
    for (int r = 0; r < 4; ++r)
      out[(size_t)(b * NC + ob + r) * NT + t] = (a[r] + bp[ob + r]) * mv;
  }
}

// ---------------------------------------------------------------------------
extern "C" void kernel_launch(void* const* d_in, const int* in_sizes, int n_in,
                              void* d_out, int out_size, void* d_ws, size_t ws_size,
                              hipStream_t stream) {
  const float* q  = (const float*)d_in[0];
  const float* k  = (const float*)d_in[1];
  const float* v  = (const float*)d_in[2];
  const void*  mr = d_in[3];
  const float* Wq = (const float*)d_in[4];
  const float* bq = (const float*)d_in[5];
  const float* Wk = (const float*)d_in[6];
  const float* bk = (const float*)d_in[7];
  const float* Wv = (const float*)d_in[8];
  const float* bv = (const float*)d_in[9];
  const float* Wp = (const float*)d_in[10];
  const float* bp = (const float*)d_in[11];
  float* out = (float*)d_out;

  // workspace layout (~62 MB)
  u16* Wc = (u16*)d_ws;                                   // 4 * 512*512 bf16
  u16* Xt = Wc + (size_t)4 * NC * NC;                     // 3 * B*T*C bf16
  u16* Qw = Xt + (size_t)3 * NB * NT * NC;                // (B,H,T,D) bf16
  u16* Kw = Qw + (size_t)NB * NT * NC;
  u16* Vw = Kw + (size_t)NB * NT * NC;                    // (B,C,T)
  float* Op    = (float*)(Vw + (size_t)NB * NT * NC);     // 2 * B*H*T*D f32
  float* ml    = Op + (size_t)2 * NB * NH * NT * ND;      // 2 * B*H*T * {m,l}
  float* maskf = ml + (size_t)2 * NB * NH * NT * 2;       // B*T floats
  float* maskb = maskf + (size_t)NB * NT;                 // B*T floats (bias)
  float* outtail = out + (size_t)NB * NC * NT;            // mask chunk of d_out

  convert_kernel<<<1025, 256, 0, stream>>>(Wq, Wk, Wv, Wp, mr, Wc, maskf, maskb, outtail);
  transpose_kernel<<<dim3(NT / 32, NC / 32, 6), dim3(32, 8), 0, stream>>>(q, k, v, Xt);
  proj_kernel<<<dim3(8, 32, 3), 256, 0, stream>>>(Wc, Xt, bq, bk, bv, Qw, Kw, Vw, maskf);
  attn_kernel<<<dim3(16, 32, 2), 256, 0, stream>>>(Qw, Kw, Vw, Op, ml, maskb);
  outproj_kernel<<<dim3(16, 64), 256, 0, stream>>>(Wc, Op, ml, bp, out, maskf);
}

// Round 5
// 263.811 us; speedup vs baseline: 1.0278x; 1.0278x over previous
//
#include <hip/hip_runtime.h>

using u16 = unsigned short;
typedef float  f32x4 __attribute__((ext_vector_type(4)));
typedef __bf16 bf8_t __attribute__((ext_vector_type(8)));
typedef u16    u16x4 __attribute__((ext_vector_type(4)));
typedef unsigned int u32x2 __attribute__((ext_vector_type(2)));

#define NB 2
#define NH 16
#define NT 2048
#define ND 32
#define NC 512
#define QK_SCALE 0.17677669529663687f   // 1/sqrt(32)
#define LOG2E    1.4426950408889634f

__device__ __forceinline__ u16 f2bf(float f) {
  unsigned int u = __float_as_uint(f);
  u += 0x7fffu + ((u >> 16) & 1u);      // RNE
  return (u16)(u >> 16);
}

__device__ __forceinline__ unsigned int cvt_pk_bf16(float a, float b) {
  unsigned int r;
  asm("v_cvt_pk_bf16_f32 %0, %1, %2" : "=v"(r) : "v"(a), "v"(b));
  return r;                             // lo16 = bf16(a), hi16 = bf16(b)
}

__device__ __forceinline__ f32x4 mfma16(bf8_t a, bf8_t b, f32x4 c) {
  return __builtin_amdgcn_mfma_f32_16x16x32_bf16(a, b, c, 0, 0, 0);
}

// ---------------------------------------------------------------------------
// Kernel 1: prep. z<6: q/k/v (B,C,T) f32 -> Xt (B,T,C) bf16 (LDS transpose).
// z==6: weights -> bf16 (Wq pre-scaled by log2e/sqrt(D)); block 0 also emits
// maskf (0/1), maskb (0/-1e30) and the mask chunk of d_out.
// ---------------------------------------------------------------------------
__global__ __launch_bounds__(256) void prep_kernel(
    const float* __restrict__ q, const float* __restrict__ k,
    const float* __restrict__ v, u16* __restrict__ Xt,
    const float* __restrict__ Wq, const float* __restrict__ Wk,
    const float* __restrict__ Wv, const float* __restrict__ Wp,
    const void* __restrict__ mraw,
    u16* __restrict__ Wc, float* __restrict__ maskf, float* __restrict__ maskb,
    float* __restrict__ outtail) {
  int z = blockIdx.z;
  int tx = threadIdx.x, ty = threadIdx.y;
  if (z == 6) {                          // weight conversion (+ mask on block 0)
    int bid = blockIdx.y * 64 + blockIdx.x;      // 0..1023
    int tid = ty * 32 + tx;
    int idx = (bid * 256 + tid) * 4;
    int m   = idx >> 18;                 // 262144 elements per matrix
    int off = idx & 262143;
    const float* W = (m == 0) ? Wq : (m == 1) ? Wk : (m == 2) ? Wv : Wp;
    float s = (m == 0) ? (QK_SCALE * LOG2E) : 1.0f;
    f32x4 wv = *(const f32x4*)(W + off);
    u16x4 pk;
    #pragma unroll
    for (int r = 0; r < 4; ++r) pk[r] = f2bf(wv[r] * s);
    *(u16x4*)(Wc + (size_t)m * (NC * NC) + off) = pk;
    if (bid == 0) {
      unsigned int w0 = *(const unsigned int*)mraw;   // bool-bytes vs int32
      bool intlay = (w0 == 1u);
      #pragma unroll
      for (int kk = 0; kk < 16; ++kk) {
        int j = tid + kk * 256;          // 0..4095 = NB*NT
        float mv;
        if (intlay) mv = ((const int*)mraw)[j] ? 1.0f : 0.0f;
        else        mv = ((const unsigned char*)mraw)[j] ? 1.0f : 0.0f;
        maskf[j]   = mv;
        maskb[j]   = (mv - 1.0f) * 1e30f;
        outtail[j] = mv;
      }
    }
    return;
  }
  __shared__ float tile[32][33];
  int m = z >> 1, b = z & 1;
  const float* src = (m == 0) ? q : (m == 1) ? k : v;
  int t0 = blockIdx.x * 32, c0 = blockIdx.y * 32;
  #pragma unroll
  for (int j = 0; j < 4; ++j)
    tile[ty + j * 8][tx] = src[(size_t)(b * NC + c0 + ty + j * 8) * NT + t0 + tx];
  __syncthreads();
  u16* dst = Xt + (size_t)m * (NB * NT * NC);
  #pragma unroll
  for (int j = 0; j < 4; ++j)
    dst[((size_t)b * NT + t0 + ty + j * 8) * NC + c0 + tx] = f2bf(tile[tx][ty + j * 8]);
}

// ---------------------------------------------------------------------------
// Kernel 2: 3 input projections (R2-proven M=64 x N=128 tile, direct frags).
// grid (8, 32, 3).  z: 0=Q -> (B,H,T,D) scaled; 1=K -> (B,H,T,D);
// 2=V -> (B,C,T) masked.
// ---------------------------------------------------------------------------
__global__ __launch_bounds__(256) void proj_kernel(
    const u16* __restrict__ Wc, const u16* __restrict__ Xt,
    const float* __restrict__ bq, const float* __restrict__ bk, const float* __restrict__ bv,
    u16* __restrict__ Qw, u16* __restrict__ Kw, u16* __restrict__ Vw,
    const float* __restrict__ maskf) {
  int z = blockIdx.z;
  const u16* W = Wc + (size_t)z * (NC * NC);
  const float* bias = (z == 0) ? bq : (z == 1) ? bk : bv;
  int tid = threadIdx.x, wid = tid >> 6, lane = tid & 63;
  int lq = lane & 15, g = lane >> 4;
  int om0 = blockIdx.x * 64;
  int b   = blockIdx.y >> 4;
  int t0  = (blockIdx.y & 15) * 128 + wid * 32;
  const u16* Xb = Xt + (size_t)z * (NB * NT * NC) + (size_t)b * NT * NC;

  const f32x4 zero = {0.f, 0.f, 0.f, 0.f};
  f32x4 acc[4][2];
  #pragma unroll
  for (int mt = 0; mt < 4; ++mt)
    #pragma unroll
    for (int nt = 0; nt < 2; ++nt) acc[mt][nt] = zero;

  for (int ks = 0; ks < 16; ++ks) {       // K = 512, BK = 32
    bf8_t af[4], bfr[2];
    #pragma unroll
    for (int mt = 0; mt < 4; ++mt)
      af[mt] = *(const bf8_t*)(W + (size_t)(om0 + mt * 16 + lq) * NC + ks * 32 + 8 * g);
    #pragma unroll
    for (int nt = 0; nt < 2; ++nt)
      bfr[nt] = *(const bf8_t*)(Xb + (size_t)(t0 + nt * 16 + lq) * NC + ks * 32 + 8 * g);
    #pragma unroll
    for (int mt = 0; mt < 4; ++mt)
      #pragma unroll
      for (int nt = 0; nt < 2; ++nt)
        acc[mt][nt] = mfma16(af[mt], bfr[nt], acc[mt][nt]);
  }

  float sc = (z == 0) ? (QK_SCALE * LOG2E) : 1.0f;
  #pragma unroll
  for (int mt = 0; mt < 4; ++mt) {
    int ob = om0 + mt * 16 + 4 * g;       // 4 consecutive output channels (regs)
    float b4[4];
    #pragma unroll
    for (int r = 0; r < 4; ++r) b4[r] = bias[ob + r] * sc;
    #pragma unroll
    for (int nt = 0; nt < 2; ++nt) {
      int t = t0 + nt * 16 + lq;
      if (z < 2) {
        u16x4 pk;
        #pragma unroll
        for (int r = 0; r < 4; ++r) pk[r] = f2bf(acc[mt][nt][r] + b4[r]);
        u16* dst = (z == 0) ? Qw : Kw;
        *(u16x4*)(dst + ((size_t)(b * NH + (ob >> 5)) * NT + t) * ND + (ob & 31)) = pk;
      } else {
        float mv = maskf[b * NT + t];     // vm = vh * mask
        #pragma unroll
        for (int r = 0; r < 4; ++r)
          Vw[(size_t)(b * NC + ob + r) * NT + t] = f2bf((acc[mt][nt][r] + b4[r]) * mv);
      }
    }
  }
}

// ---------------------------------------------------------------------------
// Kernel 3: flash attention, IN-BLOCK split-KV. 4 waves/block: waves {0,1}
// do q-subtiles {0,1} x KV half 0; waves {2,3} same q-subtiles x KV half 1.
// Per-wave structure identical to the R2 kernel (32 q-rows, K-frag feeds 2
// MFMAs). Partials combined through LDS (overlaying waves 0/1's P-tiles),
// no HBM round-trip. Grid (32,32) = 1024 blocks -> 4 waves/SIMD.
// ---------------------------------------------------------------------------
__global__ __launch_bounds__(256, 4) void attn_kernel(
    const u16* __restrict__ Qw, const u16* __restrict__ Kw, const u16* __restrict__ Vw,
    u16* __restrict__ Ow, const float* __restrict__ maskb) {
  __shared__ u16 plds[4][32][128];        // per-wave P-tile [tq][tk] bf16
  int tid = threadIdx.x, wid = tid >> 6, lane = tid & 63;
  int lq = lane & 15, g = lane >> 4;
  int bh = blockIdx.y, b = bh >> 4, h = bh & 15;
  int kvz = wid >> 1;                     // KV half
  int q0  = blockIdx.x * 64 + (wid & 1) * 32;
  const u16* Qb = Qw + (size_t)bh * NT * ND;
  const u16* Kb = Kw + (size_t)bh * NT * ND;
  const u16* Vb = Vw + (size_t)(b * NC + h * ND) * NT;
  const float* mbp = maskb + b * NT;
  char* pbase = (char*)&plds[wid][0][0];

  bf8_t ones;
  #pragma unroll
  for (int j = 0; j < 8; ++j) ones[j] = (__bf16)1.0f;

  bf8_t qf[2];                            // Q rows held for whole k-loop
  #pragma unroll
  for (int c = 0; c < 2; ++c)
    qf[c] = *(const bf8_t*)(Qb + (size_t)(q0 + c * 16 + lq) * ND + 8 * g);

  const f32x4 zero = {0.f, 0.f, 0.f, 0.f};
  f32x4 acc[3][2];                        // [0..1]=O^T frags, [2]=row-sum
  #pragma unroll
  for (int dt = 0; dt < 3; ++dt)
    #pragma unroll
    for (int c = 0; c < 2; ++c) acc[dt][c] = zero;
  float mrun[2] = {0.f, 0.f};             // running max (log2 units)

  for (int kt = kvz * 8; kt < kvz * 8 + 8; ++kt) {   // this wave's KV half
    int tkb = kt * 128;
    // S^T = K @ Q^T + mask_bias (bias rides C-in; C/D row = tk)
    f32x4 st[8][2];
    #pragma unroll
    for (int rt = 0; rt < 8; ++rt) {
      f32x4 bias = *(const f32x4*)(mbp + tkb + rt * 16 + 4 * g);
      bf8_t kf = *(const bf8_t*)(Kb + (size_t)(tkb + rt * 16 + lq) * ND + 8 * g);
      st[rt][0] = mfma16(kf, qf[0], bias);
      st[rt][1] = mfma16(kf, qf[1], bias);
    }
    // V fragments: issue now, consumed after softmax (latency hides under exp)
    bf8_t vf[2][4];
    #pragma unroll
    for (int dt = 0; dt < 2; ++dt)
      #pragma unroll
      for (int kk = 0; kk < 4; ++kk)
        vf[dt][kk] = *(const bf8_t*)(Vb + (size_t)(dt * 16 + lq) * NT + tkb + kk * 32 + 8 * g);

    // online softmax per tq (lane-local in lane&15)
    #pragma unroll
    for (int c = 0; c < 2; ++c) {
      float tm = -1e30f;
      #pragma unroll
      for (int rt = 0; rt < 8; ++rt) {
        tm = fmaxf(fmaxf(st[rt][c][0], st[rt][c][1]), tm);
        tm = fmaxf(fmaxf(st[rt][c][2], st[rt][c][3]), tm);
      }
      tm = fmaxf(tm, __shfl_xor(tm, 16));
      tm = fmaxf(tm, __shfl_xor(tm, 32));
      if (__any(tm > mrun[c] + 2.0f)) {   // defer-max: rescale rarely
        float mnew = fmaxf(mrun[c], tm);
        float al = __builtin_amdgcn_exp2f(mrun[c] - mnew);
        mrun[c] = mnew;
        acc[0][c] *= al; acc[1][c] *= al; acc[2][c] *= al;
      }
      float nm = -mrun[c];
      int row = c * 16 + lq;
      #pragma unroll
      for (int rt = 0; rt < 8; ++rt) {    // exp2 + pack + LDS write
        float p0 = __builtin_amdgcn_exp2f(st[rt][c][0] + nm);
        float p1 = __builtin_amdgcn_exp2f(st[rt][c][1] + nm);
        float p2 = __builtin_amdgcn_exp2f(st[rt][c][2] + nm);
        float p3 = __builtin_amdgcn_exp2f(st[rt][c][3] + nm);
        u32x2 w;
        w[0] = cvt_pk_bf16(p0, p1);
        w[1] = cvt_pk_bf16(p2, p3);
        *(u32x2*)(pbase + row * 256 + ((rt * 32 + 8 * g) ^ ((row & 7) << 4))) = w;
      }
    }
    // O^T += V @ P^T ; row-sum += ones @ P^T (matrix pipe)
    #pragma unroll
    for (int kk = 0; kk < 4; ++kk) {
      bf8_t pf[2];
      #pragma unroll
      for (int c = 0; c < 2; ++c) {
        int row = c * 16 + lq;
        pf[c] = *(const bf8_t*)(pbase + row * 256 + ((kk * 64 + 16 * g) ^ ((row & 7) << 4)));
      }
      #pragma unroll
      for (int c = 0; c < 2; ++c) {
        acc[0][c] = mfma16(vf[0][kk], pf[c], acc[0][c]);
        acc[1][c] = mfma16(vf[1][kk], pf[c], acc[1][c]);
        acc[2][c] = mfma16(ones,      pf[c], acc[2][c]);
      }
    }
  }

  // ---- in-block combine: waves 2,3 publish partials via LDS -------------
  __syncthreads();                        // waves 0,1 done reading P-tiles
  float* cb = (float*)plds;               // overlay plds[0..1] (16 KB)
  if (wid >= 2) {
    int p = wid - 2;
    char* cbO = (char*)(cb + p * 1024);   // 32 rows x 128 B
    float* cbML = cb + 2048 + p * 64;     // 32 rows x {m,l}
    #pragma unroll
    for (int c = 0; c < 2; ++c) {
      int row = c * 16 + lq;
      #pragma unroll
      for (int dt = 0; dt < 2; ++dt)
        *(f32x4*)(cbO + row * 128 + ((dt * 64 + g * 16) ^ ((lq & 7) << 4))) = acc[dt][c];
      if (g == 0) {
        float2 mlv; mlv.x = mrun[c]; mlv.y = acc[2][c][0];
        *(float2*)(cbML + row * 2) = mlv;
      }
    }
  }
  __syncthreads();
  if (wid < 2) {
    char* cbO = (char*)(cb + wid * 1024);
    float* cbML = cb + 2048 + wid * 64;
    #pragma unroll
    for (int c = 0; c < 2; ++c) {
      int row = c * 16 + lq;
      float2 ml2 = *(const float2*)(cbML + row * 2);
      float m  = fmaxf(mrun[c], ml2.x);
      float e1 = __builtin_amdgcn_exp2f(mrun[c] - m);
      float e2 = __builtin_amdgcn_exp2f(ml2.x - m);
      float inv = 1.0f / (acc[2][c][0] * e1 + ml2.y * e2);
      float c1 = e1 * inv, c2 = e2 * inv;
      int t = q0 + row;
      #pragma unroll
      for (int dt = 0; dt < 2; ++dt) {
        f32x4 o2 = *(const f32x4*)(cbO + row * 128 + ((dt * 64 + g * 16) ^ ((lq & 7) << 4)));
        u32x2 o;
        o[0] = cvt_pk_bf16(acc[dt][c][0] * c1 + o2[0] * c2,
                           acc[dt][c][1] * c1 + o2[1] * c2);
        o[1] = cvt_pk_bf16(acc[dt][c][2] * c1 + o2[2] * c2,
                           acc[dt][c][3] * c1 + o2[3] * c2);
        *(u32x2*)(Ow + ((size_t)bh * NT + t) * ND + dt * 16 + 4 * g) = o;
      }
    }
  }
}

// ---------------------------------------------------------------------------
// Kernel 4: output projection Wp @ O + bp, times mask, f32 into d_out.
// (R2-proven M=64 x N=128 form, grid (8,32).)
// ---------------------------------------------------------------------------
__global__ __launch_bounds__(256) void outproj_kernel(
    const u16* __restrict__ Wc, const u16* __restrict__ Ow,
    const float* __restrict__ bp, float* __restrict__ out,
    const float* __restrict__ maskf) {
  const u16* W = Wc + (size_t)3 * NC * NC;
  int tid = threadIdx.x, wid = tid >> 6, lane = tid & 63;
  int lq = lane & 15, g = lane >> 4;
  int om0 = blockIdx.x * 64;
  int b   = blockIdx.y >> 4;
  int t0  = (blockIdx.y & 15) * 128 + wid * 32;
  const u16* Ob = Ow + (size_t)b * NH * NT * ND;

  const f32x4 zero = {0.f, 0.f, 0.f, 0.f};
  f32x4 acc[4][2];
  #pragma unroll
  for (int mt = 0; mt < 4; ++mt)
    #pragma unroll
    for (int nt = 0; nt < 2; ++nt) acc[mt][nt] = zero;

  for (int ks = 0; ks < 16; ++ks) {       // ks == head index; d-block = 8g
    bf8_t af[4], bfr[2];
    #pragma unroll
    for (int mt = 0; mt < 4; ++mt)
      af[mt] = *(const bf8_t*)(W + (size_t)(om0 + mt * 16 + lq) * NC + ks * 32 + 8 * g);
    #pragma unroll
    for (int nt = 0; nt < 2; ++nt)
      bfr[nt] = *(const bf8_t*)(Ob + ((size_t)ks * NT + t0 + nt * 16 + lq) * ND + 8 * g);
    #pragma unroll
    for (int mt = 0; mt < 4; ++mt)
      #pragma unroll
      for (int nt = 0; nt < 2; ++nt)
        acc[mt][nt] = mfma16(af[mt], bfr[nt], acc[mt][nt]);
  }
  #pragma unroll
  for (int mt = 0; mt < 4; ++mt) {
    int ob = om0 + mt * 16 + 4 * g;
    float b4[4];
    #pragma unroll
    for (int r = 0; r < 4; ++r) b4[r] = bp[ob + r];
    #pragma unroll
    for (int nt = 0; nt < 2; ++nt) {
      int t = t0 + nt * 16 + lq;
      float mv = maskf[b * NT + t];
      #pragma unroll
      for (int r = 0; r < 4; ++r)
        out[(size_t)(b * NC + ob + r) * NT + t] = (acc[mt][nt][r] + b4[r]) * mv;
    }
  }
}

// ---------------------------------------------------------------------------
extern "C" void kernel_launch(void* const* d_in, const int* in_sizes, int n_in,
                              void* d_out, int out_size, void* d_ws, size_t ws_size,
                              hipStream_t stream) {
  const float* q  = (const float*)d_in[0];
  const float* k  = (const float*)d_in[1];
  const float* v  = (const float*)d_in[2];
  const void*  mr = d_in[3];
  const float* Wq = (const float*)d_in[4];
  const float* bq = (const float*)d_in[5];
  const float* Wk = (const float*)d_in[6];
  const float* bk = (const float*)d_in[7];
  const float* Wv = (const float*)d_in[8];
  const float* bv = (const float*)d_in[9];
  const float* Wp = (const float*)d_in[10];
  const float* bp = (const float*)d_in[11];
  float* out = (float*)d_out;

  // workspace layout (~30 MB)
  u16* Wc = (u16*)d_ws;                                   // 4 * 512*512 bf16
  u16* Xt = Wc + (size_t)4 * NC * NC;                     // 3 * B*T*C bf16
  u16* Qw = Xt + (size_t)3 * NB * NT * NC;                // (B,H,T,D) bf16
  u16* Kw = Qw + (size_t)NB * NT * NC;
  u16* Vw = Kw + (size_t)NB * NT * NC;                    // (B,C,T)
  u16* Ow = Vw + (size_t)NB * NT * NC;                    // (B,H,T,D)
  float* maskf   = (float*)(Ow + (size_t)NB * NT * NC);   // B*T floats
  float* maskb   = maskf + (size_t)NB * NT;               // B*T floats (bias)
  float* outtail = out + (size_t)NB * NC * NT;            // mask chunk of d_out

  prep_kernel<<<dim3(64, 16, 7), dim3(32, 8), 0, stream>>>(
      q, k, v, Xt, Wq, Wk, Wv, Wp, mr, Wc, maskf, maskb, outtail);
  proj_kernel<<<dim3(8, 32, 3), 256, 0, stream>>>(Wc, Xt, bq, bk, bv, Qw, Kw, Vw, maskf);
  attn_kernel<<<dim3(32, 32), 256, 0, stream>>>(Qw, Kw, Vw, Ow, maskb);
  outproj_kernel<<<dim3(8, 32), 256, 0, stream>>>(Wc, Ow, bp, out, maskf);
}

// Round 6
// 207.078 us; speedup vs baseline: 1.3094x; 1.2740x over previous
//
#include <hip/hip_runtime.h>

using u16 = unsigned short;
typedef float  f32x4 __attribute__((ext_vector_type(4)));
typedef __bf16 bf8_t __attribute__((ext_vector_type(8)));
typedef u16    u16x4 __attribute__((ext_vector_type(4)));
typedef unsigned int u32x2 __attribute__((ext_vector_type(2)));

#define NB 2
#define NH 16
#define NT 2048
#define ND 32
#define NC 512
#define QK_SCALE 0.17677669529663687f   // 1/sqrt(32)
#define LOG2E    1.4426950408889634f

__device__ __forceinline__ u16 f2bf(float f) {
  unsigned int u = __float_as_uint(f);
  u += 0x7fffu + ((u >> 16) & 1u);      // RNE
  return (u16)(u >> 16);
}

__device__ __forceinline__ unsigned int cvt_pk_bf16(float a, float b) {
  unsigned int r;
  asm("v_cvt_pk_bf16_f32 %0, %1, %2" : "=v"(r) : "v"(a), "v"(b));
  return r;                             // lo16 = bf16(a), hi16 = bf16(b)
}

__device__ __forceinline__ f32x4 mfma16(bf8_t a, bf8_t b, f32x4 c) {
  return __builtin_amdgcn_mfma_f32_16x16x32_bf16(a, b, c, 0, 0, 0);
}

// ---------------------------------------------------------------------------
// Kernel 1: prep. z<6: q/k/v (B,C,T) f32 -> Xt (B,T,C) bf16 (LDS transpose).
// z==6: weights -> bf16 (Wq pre-scaled by log2e/sqrt(D)); block 0 also emits
// maskf (0/1), maskb (0/-1e30) and the mask chunk of d_out.
// ---------------------------------------------------------------------------
__global__ __launch_bounds__(256) void prep_kernel(
    const float* __restrict__ q, const float* __restrict__ k,
    const float* __restrict__ v, u16* __restrict__ Xt,
    const float* __restrict__ Wq, const float* __restrict__ Wk,
    const float* __restrict__ Wv, const float* __restrict__ Wp,
    const void* __restrict__ mraw,
    u16* __restrict__ Wc, float* __restrict__ maskf, float* __restrict__ maskb,
    float* __restrict__ outtail) {
  int z = blockIdx.z;
  int tx = threadIdx.x, ty = threadIdx.y;
  if (z == 6) {                          // weight conversion (+ mask on block 0)
    int bid = blockIdx.y * 64 + blockIdx.x;      // 0..1023
    int tid = ty * 32 + tx;
    int idx = (bid * 256 + tid) * 4;
    int m   = idx >> 18;                 // 262144 elements per matrix
    int off = idx & 262143;
    const float* W = (m == 0) ? Wq : (m == 1) ? Wk : (m == 2) ? Wv : Wp;
    float s = (m == 0) ? (QK_SCALE * LOG2E) : 1.0f;
    f32x4 wv = *(const f32x4*)(W + off);
    u16x4 pk;
    #pragma unroll
    for (int r = 0; r < 4; ++r) pk[r] = f2bf(wv[r] * s);
    *(u16x4*)(Wc + (size_t)m * (NC * NC) + off) = pk;
    if (bid == 0) {
      unsigned int w0 = *(const unsigned int*)mraw;   // bool-bytes vs int32
      bool intlay = (w0 == 1u);
      #pragma unroll
      for (int kk = 0; kk < 16; ++kk) {
        int j = tid + kk * 256;          // 0..4095 = NB*NT
        float mv;
        if (intlay) mv = ((const int*)mraw)[j] ? 1.0f : 0.0f;
        else        mv = ((const unsigned char*)mraw)[j] ? 1.0f : 0.0f;
        maskf[j]   = mv;
        maskb[j]   = (mv - 1.0f) * 1e30f;
        outtail[j] = mv;
      }
    }
    return;
  }
  __shared__ float tile[32][33];
  int m = z >> 1, b = z & 1;
  const float* src = (m == 0) ? q : (m == 1) ? k : v;
  int t0 = blockIdx.x * 32, c0 = blockIdx.y * 32;
  #pragma unroll
  for (int j = 0; j < 4; ++j)
    tile[ty + j * 8][tx] = src[(size_t)(b * NC + c0 + ty + j * 8) * NT + t0 + tx];
  __syncthreads();
  u16* dst = Xt + (size_t)m * (NB * NT * NC);
  #pragma unroll
  for (int j = 0; j < 4; ++j)
    dst[((size_t)b * NT + t0 + ty + j * 8) * NC + c0 + tx] = f2bf(tile[tx][ty + j * 8]);
}

// ---------------------------------------------------------------------------
// Kernel 2: 3 input projections (R2-proven M=64 x N=128 tile, direct frags).
// grid (8, 32, 3).  z: 0=Q -> (B,H,T,D) scaled; 1=K -> (B,H,T,D);
// 2=V -> (B,C,T) masked.
// ---------------------------------------------------------------------------
__global__ __launch_bounds__(256) void proj_kernel(
    const u16* __restrict__ Wc, const u16* __restrict__ Xt,
    const float* __restrict__ bq, const float* __restrict__ bk, const float* __restrict__ bv,
    u16* __restrict__ Qw, u16* __restrict__ Kw, u16* __restrict__ Vw,
    const float* __restrict__ maskf) {
  int z = blockIdx.z;
  const u16* W = Wc + (size_t)z * (NC * NC);
  const float* bias = (z == 0) ? bq : (z == 1) ? bk : bv;
  int tid = threadIdx.x, wid = tid >> 6, lane = tid & 63;
  int lq = lane & 15, g = lane >> 4;
  int om0 = blockIdx.x * 64;
  int b   = blockIdx.y >> 4;
  int t0  = (blockIdx.y & 15) * 128 + wid * 32;
  const u16* Xb = Xt + (size_t)z * (NB * NT * NC) + (size_t)b * NT * NC;

  const f32x4 zero = {0.f, 0.f, 0.f, 0.f};
  f32x4 acc[4][2];
  #pragma unroll
  for (int mt = 0; mt < 4; ++mt)
    #pragma unroll
    for (int nt = 0; nt < 2; ++nt) acc[mt][nt] = zero;

  for (int ks = 0; ks < 16; ++ks) {       // K = 512, BK = 32
    bf8_t af[4], bfr[2];
    #pragma unroll
    for (int mt = 0; mt < 4; ++mt)
      af[mt] = *(const bf8_t*)(W + (size_t)(om0 + mt * 16 + lq) * NC + ks * 32 + 8 * g);
    #pragma unroll
    for (int nt = 0; nt < 2; ++nt)
      bfr[nt] = *(const bf8_t*)(Xb + (size_t)(t0 + nt * 16 + lq) * NC + ks * 32 + 8 * g);
    #pragma unroll
    for (int mt = 0; mt < 4; ++mt)
      #pragma unroll
      for (int nt = 0; nt < 2; ++nt)
        acc[mt][nt] = mfma16(af[mt], bfr[nt], acc[mt][nt]);
  }

  float sc = (z == 0) ? (QK_SCALE * LOG2E) : 1.0f;
  #pragma unroll
  for (int mt = 0; mt < 4; ++mt) {
    int ob = om0 + mt * 16 + 4 * g;       // 4 consecutive output channels (regs)
    float b4[4];
    #pragma unroll
    for (int r = 0; r < 4; ++r) b4[r] = bias[ob + r] * sc;
    #pragma unroll
    for (int nt = 0; nt < 2; ++nt) {
      int t = t0 + nt * 16 + lq;
      if (z < 2) {
        u16x4 pk;
        #pragma unroll
        for (int r = 0; r < 4; ++r) pk[r] = f2bf(acc[mt][nt][r] + b4[r]);
        u16* dst = (z == 0) ? Qw : Kw;
        *(u16x4*)(dst + ((size_t)(b * NH + (ob >> 5)) * NT + t) * ND + (ob & 31)) = pk;
      } else {
        float mv = maskf[b * NT + t];     // vm = vh * mask
        #pragma unroll
        for (int r = 0; r < 4; ++r)
          Vw[(size_t)(b * NC + ob + r) * NT + t] = f2bf((acc[mt][nt][r] + b4[r]) * mv);
      }
    }
  }
}

// ---------------------------------------------------------------------------
// Kernel 3: flash attention, IN-BLOCK split-KV, spill-free build.
// 4 waves/block: waves {0,1} = q-subtiles {0,1} x KV half 0; waves {2,3}
// same q-subtiles x KV half 1. Grid (32,32) = 1024 blocks.
// NO launch_bounds min-arg (R5's spill cause). V fragments loaded between
// the two per-subtile softmax passes (latency hidden, -32 VGPRs of preload).
// Partials combined through LDS overlay; no HBM round-trip.
// ---------------------------------------------------------------------------
__global__ __launch_bounds__(256) void attn_kernel(
    const u16* __restrict__ Qw, const u16* __restrict__ Kw, const u16* __restrict__ Vw,
    u16* __restrict__ Ow, const float* __restrict__ maskb) {
  __shared__ u16 plds[4][32][128];        // per-wave P-tile [tq][tk] bf16
  int tid = threadIdx.x, wid = tid >> 6, lane = tid & 63;
  int lq = lane & 15, g = lane >> 4;
  int bh = blockIdx.y, b = bh >> 4, h = bh & 15;
  int kvz = wid >> 1;                     // KV half
  int q0  = blockIdx.x * 64 + (wid & 1) * 32;
  const u16* Qb = Qw + (size_t)bh * NT * ND;
  const u16* Kb = Kw + (size_t)bh * NT * ND;
  const u16* Vb = Vw + (size_t)(b * NC + h * ND) * NT;
  const float* mbp = maskb + b * NT;
  char* pbase = (char*)&plds[wid][0][0];

  bf8_t ones;
  #pragma unroll
  for (int j = 0; j < 8; ++j) ones[j] = (__bf16)1.0f;

  bf8_t qf[2];                            // Q rows held for whole k-loop
  #pragma unroll
  for (int c = 0; c < 2; ++c)
    qf[c] = *(const bf8_t*)(Qb + (size_t)(q0 + c * 16 + lq) * ND + 8 * g);

  const f32x4 zero = {0.f, 0.f, 0.f, 0.f};
  f32x4 acc[3][2];                        // [0..1]=O^T frags, [2]=row-sum
  #pragma unroll
  for (int dt = 0; dt < 3; ++dt)
    #pragma unroll
    for (int c = 0; c < 2; ++c) acc[dt][c] = zero;
  float mrun[2] = {0.f, 0.f};             // running max (log2 units)

  // one softmax pass for q-subtile c: max-reduce, defer-max, exp2+pack->LDS
  #define SOFTMAX_PASS(c)                                                   \
    {                                                                       \
      float tm = -1e30f;                                                    \
      _Pragma("unroll")                                                     \
      for (int rt = 0; rt < 8; ++rt) {                                      \
        tm = fmaxf(fmaxf(st[rt][c][0], st[rt][c][1]), tm);                  \
        tm = fmaxf(fmaxf(st[rt][c][2], st[rt][c][3]), tm);                  \
      }                                                                     \
      tm = fmaxf(tm, __shfl_xor(tm, 16));                                   \
      tm = fmaxf(tm, __shfl_xor(tm, 32));                                   \
      if (__any(tm > mrun[c] + 2.0f)) {                                     \
        float mnew = fmaxf(mrun[c], tm);                                    \
        float al = __builtin_amdgcn_exp2f(mrun[c] - mnew);                  \
        mrun[c] = mnew;                                                     \
        acc[0][c] *= al; acc[1][c] *= al; acc[2][c] *= al;                  \
      }                                                                     \
      float nm = -mrun[c];                                                  \
      int row = c * 16 + lq;                                                \
      _Pragma("unroll")                                                     \
      for (int rt = 0; rt < 8; ++rt) {                                      \
        float p0 = __builtin_amdgcn_exp2f(st[rt][c][0] + nm);               \
        float p1 = __builtin_amdgcn_exp2f(st[rt][c][1] + nm);               \
        float p2 = __builtin_amdgcn_exp2f(st[rt][c][2] + nm);               \
        float p3 = __builtin_amdgcn_exp2f(st[rt][c][3] + nm);               \
        u32x2 w;                                                            \
        w[0] = cvt_pk_bf16(p0, p1);                                         \
        w[1] = cvt_pk_bf16(p2, p3);                                         \
        *(u32x2*)(pbase + row * 256 + ((rt * 32 + 8 * g) ^ ((row & 7) << 4))) = w; \
      }                                                                     \
    }

  for (int kt = kvz * 8; kt < kvz * 8 + 8; ++kt) {   // this wave's KV half
    int tkb = kt * 128;
    // S^T = K @ Q^T + mask_bias (bias rides C-in; C/D row = tk)
    f32x4 st[8][2];
    #pragma unroll
    for (int rt = 0; rt < 8; ++rt) {
      f32x4 bias = *(const f32x4*)(mbp + tkb + rt * 16 + 4 * g);
      bf8_t kf = *(const bf8_t*)(Kb + (size_t)(tkb + rt * 16 + lq) * ND + 8 * g);
      st[rt][0] = mfma16(kf, qf[0], bias);
      st[rt][1] = mfma16(kf, qf[1], bias);
    }
    SOFTMAX_PASS(0)
    // V fragments issued here: c=1 softmax (~60 VALU ops) hides L2 latency;
    // st[*][0] is dead now so register pressure stays ~flat.
    bf8_t vf[2][4];
    #pragma unroll
    for (int dt = 0; dt < 2; ++dt)
      #pragma unroll
      for (int kk = 0; kk < 4; ++kk)
        vf[dt][kk] = *(const bf8_t*)(Vb + (size_t)(dt * 16 + lq) * NT + tkb + kk * 32 + 8 * g);
    SOFTMAX_PASS(1)
    // O^T += V @ P^T ; row-sum += ones @ P^T (matrix pipe)
    #pragma unroll
    for (int kk = 0; kk < 4; ++kk) {
      bf8_t pf[2];
      #pragma unroll
      for (int c = 0; c < 2; ++c) {
        int row = c * 16 + lq;
        pf[c] = *(const bf8_t*)(pbase + row * 256 + ((kk * 64 + 16 * g) ^ ((row & 7) << 4)));
      }
      #pragma unroll
      for (int c = 0; c < 2; ++c) {
        acc[0][c] = mfma16(vf[0][kk], pf[c], acc[0][c]);
        acc[1][c] = mfma16(vf[1][kk], pf[c], acc[1][c]);
        acc[2][c] = mfma16(ones,      pf[c], acc[2][c]);
      }
    }
  }
  #undef SOFTMAX_PASS

  // ---- in-block combine: waves 2,3 publish partials via LDS -------------
  __syncthreads();                        // waves 0,1 done reading P-tiles
  float* cb = (float*)plds;               // overlay plds[0..1] (16 KB)
  if (wid >= 2) {
    int p = wid - 2;
    char* cbO = (char*)(cb + p * 1024);   // 32 rows x 128 B
    float* cbML = cb + 2048 + p * 64;     // 32 rows x {m,l}
    #pragma unroll
    for (int c = 0; c < 2; ++c) {
      int row = c * 16 + lq;
      #pragma unroll
      for (int dt = 0; dt < 2; ++dt)
        *(f32x4*)(cbO + row * 128 + ((dt * 64 + g * 16) ^ ((lq & 7) << 4))) = acc[dt][c];
      if (g == 0) {
        float2 mlv; mlv.x = mrun[c]; mlv.y = acc[2][c][0];
        *(float2*)(cbML + row * 2) = mlv;
      }
    }
  }
  __syncthreads();
  if (wid < 2) {
    char* cbO = (char*)(cb + wid * 1024);
    float* cbML = cb + 2048 + wid * 64;
    #pragma unroll
    for (int c = 0; c < 2; ++c) {
      int row = c * 16 + lq;
      float2 ml2 = *(const float2*)(cbML + row * 2);
      float m  = fmaxf(mrun[c], ml2.x);
      float e1 = __builtin_amdgcn_exp2f(mrun[c] - m);
      float e2 = __builtin_amdgcn_exp2f(ml2.x - m);
      float inv = 1.0f / (acc[2][c][0] * e1 + ml2.y * e2);
      float c1 = e1 * inv, c2 = e2 * inv;
      int t = q0 + row;
      #pragma unroll
      for (int dt = 0; dt < 2; ++dt) {
        f32x4 o2 = *(const f32x4*)(cbO + row * 128 + ((dt * 64 + g * 16) ^ ((lq & 7) << 4)));
        u32x2 o;
        o[0] = cvt_pk_bf16(acc[dt][c][0] * c1 + o2[0] * c2,
                           acc[dt][c][1] * c1 + o2[1] * c2);
        o[1] = cvt_pk_bf16(acc[dt][c][2] * c1 + o2[2] * c2,
                           acc[dt][c][3] * c1 + o2[3] * c2);
        *(u32x2*)(Ow + ((size_t)bh * NT + t) * ND + dt * 16 + 4 * g) = o;
      }
    }
  }
}

// ---------------------------------------------------------------------------
// Kernel 4: output projection Wp @ O + bp, times mask, f32 into d_out.
// (R2-proven M=64 x N=128 form, grid (8,32).)
// ---------------------------------------------------------------------------
__global__ __launch_bounds__(256) void outproj_kernel(
    const u16* __restrict__ Wc, const u16* __restrict__ Ow,
    const float* __restrict__ bp, float* __restrict__ out,
    const float* __restrict__ maskf) {
  const u16* W = Wc + (size_t)3 * NC * NC;
  int tid = threadIdx.x, wid = tid >> 6, lane = tid & 63;
  int lq = lane & 15, g = lane >> 4;
  int om0 = blockIdx.x * 64;
  int b   = blockIdx.y >> 4;
  int t0  = (blockIdx.y & 15) * 128 + wid * 32;
  const u16* Ob = Ow + (size_t)b * NH * NT * ND;

  const f32x4 zero = {0.f, 0.f, 0.f, 0.f};
  f32x4 acc[4][2];
  #pragma unroll
  for (int mt = 0; mt < 4; ++mt)
    #pragma unroll
    for (int nt = 0; nt < 2; ++nt) acc[mt][nt] = zero;

  for (int ks = 0; ks < 16; ++ks) {       // ks == head index; d-block = 8g
    bf8_t af[4], bfr[2];
    #pragma unroll
    for (int mt = 0; mt < 4; ++mt)
      af[mt] = *(const bf8_t*)(W + (size_t)(om0 + mt * 16 + lq) * NC + ks * 32 + 8 * g);
    #pragma unroll
    for (int nt = 0; nt < 2; ++nt)
      bfr[nt] = *(const bf8_t*)(Ob + ((size_t)ks * NT + t0 + nt * 16 + lq) * ND + 8 * g);
    #pragma unroll
    for (int mt = 0; mt < 4; ++mt)
      #pragma unroll
      for (int nt = 0; nt < 2; ++nt)
        acc[mt][nt] = mfma16(af[mt], bfr[nt], acc[mt][nt]);
  }
  #pragma unroll
  for (int mt = 0; mt < 4; ++mt) {
    int ob = om0 + mt * 16 + 4 * g;
    float b4[4];
    #pragma unroll
    for (int r = 0; r < 4; ++r) b4[r] = bp[ob + r];
    #pragma unroll
    for (int nt = 0; nt < 2; ++nt) {
      int t = t0 + nt * 16 + lq;
      float mv = maskf[b * NT + t];
      #pragma unroll
      for (int r = 0; r < 4; ++r)
        out[(size_t)(b * NC + ob + r) * NT + t] = (acc[mt][nt][r] + b4[r]) * mv;
    }
  }
}

// ---------------------------------------------------------------------------
extern "C" void kernel_launch(void* const* d_in, const int* in_sizes, int n_in,
                              void* d_out, int out_size, void* d_ws, size_t ws_size,
                              hipStream_t stream) {
  const float* q  = (const float*)d_in[0];
  const float* k  = (const float*)d_in[1];
  const float* v  = (const float*)d_in[2];
  const void*  mr = d_in[3];
  const float* Wq = (const float*)d_in[4];
  const float* bq = (const float*)d_in[5];
  const float* Wk = (const float*)d_in[6];
  const float* bk = (const float*)d_in[7];
  const float* Wv = (const float*)d_in[8];
  const float* bv = (const float*)d_in[9];
  const float* Wp = (const float*)d_in[10];
  const float* bp = (const float*)d_in[11];
  float* out = (float*)d_out;

  // workspace layout (~30 MB)
  u16* Wc = (u16*)d_ws;                                   // 4 * 512*512 bf16
  u16* Xt = Wc + (size_t)4 * NC * NC;                     // 3 * B*T*C bf16
  u16* Qw = Xt + (size_t)3 * NB * NT * NC;                // (B,H,T,D) bf16
  u16* Kw = Qw + (size_t)NB * NT * NC;
  u16* Vw = Kw + (size_t)NB * NT * NC;                    // (B,C,T)
  u16* Ow = Vw + (size_t)NB * NT * NC;                    // (B,H,T,D)
  float* maskf   = (float*)(Ow + (size_t)NB * NT * NC);   // B*T floats
  float* maskb   = maskf + (size_t)NB * NT;               // B*T floats (bias)
  float* outtail = out + (size_t)NB * NC * NT;            // mask chunk of d_out

  prep_kernel<<<dim3(64, 16, 7), dim3(32, 8), 0, stream>>>(
      q, k, v, Xt, Wq, Wk, Wv, Wp, mr, Wc, maskf, maskb, outtail);
  proj_kernel<<<dim3(8, 32, 3), 256, 0, stream>>>(Wc, Xt, bq, bk, bv, Qw, Kw, Vw, maskf);
  attn_kernel<<<dim3(32, 32), 256, 0, stream>>>(Qw, Kw, Vw, Ow, maskb);
  outproj_kernel<<<dim3(8, 32), 256, 0, stream>>>(Wc, Ow, bp, out, maskf);
}